// Round 14
// baseline (2408.119 us; speedup 1.0000x reference)
//
#include <hip/hip_runtime.h>

#define EPSV 1e-5f
typedef unsigned short u16;
typedef short bf16x8 __attribute__((ext_vector_type(8)));
typedef float f32x4 __attribute__((ext_vector_type(4)));
typedef u16 u16x8 __attribute__((ext_vector_type(8)));

__device__ __forceinline__ float gelu_exact(float x) {
    return 0.5f * x * (1.0f + erff(x * 0.7071067811865475f));
}
__device__ __forceinline__ u16 to_bf(float x) {
    union { float f; unsigned u; } c; c.f = x;
    unsigned r = c.u + 0x7fffu + ((c.u >> 16) & 1u);
    return (u16)(r >> 16);
}
__device__ __forceinline__ float to_f(u16 h) {
    union { unsigned u; float f; } c; c.u = ((unsigned)h) << 16;
    return c.f;
}
__device__ __forceinline__ void gload_lds16(const void* g, void* l) {
    __builtin_amdgcn_global_load_lds((const __attribute__((address_space(1))) unsigned int*)g,
                                     (__attribute__((address_space(3))) unsigned int*)l, 16, 0, 0);
}
// bijective XCD-aware swizzle (m204)
__device__ __forceinline__ int xcd_swz() {
    int nwg = gridDim.x, orig = blockIdx.x;
    int q = nwg >> 3, r = nwg & 7;
    int xcd = orig & 7, sub = orig >> 3;
    return ((xcd < r) ? xcd * (q + 1) : r * (q + 1) + (xcd - r) * q) + sub;
}

// ---------------- guard ----------------
__global__ void k_wsfail(float* out) { out[0] = 1.0e9f; }

// ---------------- combined setup ----------------
__global__ void k_setup(float* __restrict__ sacc,
                        const float* __restrict__ conv1_w, float* __restrict__ w1t,
                        const float* __restrict__ conv2_w, u16* __restrict__ wpack,
                        const float* __restrict__ b1, const float* __restrict__ b2,
                        float* __restrict__ bias12,
                        float* __restrict__ postab, float* __restrict__ ropetab,
                        const float* __restrict__ cls, float* __restrict__ xa) {
    int idx = blockIdx.x * 256 + threadIdx.x;   // 512 blocks -> 131072
    if (idx < 131072) {
        int p = idx >> 9, j = idx & 511;
        float coord = (j < 256) ? (float)(p >> 4) : (float)(p & 15);
        int jm = j & 127;
        float om = powf(10000.0f, -(float)jm / 128.0f);
        float arg = coord * om;
        postab[idx] = ((j >> 7) & 1) ? cosf(arg) : sinf(arg);
    }
    if (idx < 512) {
        // xpos tables indexed by HEAD h (reference quirk): n_pos = H = 8
        int h = idx >> 6, d = idx & 63;
        float freq = (float)h * powf(10000.0f, -(float)(d >> 1) / 32.0f);
        float sv = (2.0f * (float)(d & 31) + 25.6f) / 89.6f;
        float pw = ((float)h - 4.0f) / 512.0f;
        float sc = powf(sv, pw);
        ropetab[idx * 4 + 0] = cosf(freq);
        ropetab[idx * 4 + 1] = sinf(freq);
        ropetab[idx * 4 + 2] = sc * 0.125f;
        ropetab[idx * 4 + 3] = 1.0f / sc;
    }
    if (idx < 768) sacc[idx] = 0.0f;
    if (idx < 864) {
        int co = idx / 27, k = idx % 27;
        w1t[k * 32 + co] = conv1_w[idx];
    }
    if (idx < 18432) {
        int ci = idx & 31, tc = idx >> 5;
        int tap = tc >> 6, co = tc & 63;
        wpack[idx] = to_bf(conv2_w[co * 288 + ci * 9 + tap]);
    }
    if (idx < 32768) {
        int l = idx >> 12, pc = idx & 4095;
        int chunk = pc >> 4, within = pc & 15;
        int srccol = (chunk >> 1) * 16 + within;
        bias12[idx] = (chunk & 1) ? b2[l * 2048 + srccol] : b1[l * 2048 + srccol];
    }
    if (idx < 16384) {
        int b = idx >> 9, d = idx & 511;
        xa[(size_t)(b * 257) * 512 + d] = cls[d];
    }
}

// patch_w [512][64][8][8] -> bf16 [cout][tap*64+ci]
__global__ void k_pperm(const float* __restrict__ w, u16* __restrict__ wp) {
    int idx = blockIdx.x * 256 + threadIdx.x;
    int cout = idx >> 12, rem = idx & 4095;
    int tap = rem >> 6, ci = rem & 63;
    wp[idx] = to_bf(w[cout * 4096 + ci * 64 + tap]);
}

// fp32 [K][N] -> bf16 [N][K] transpose-convert (z = layer)
__global__ __launch_bounds__(256) void k_wcvtT(const float* __restrict__ src,
                                               u16* __restrict__ dst, int K, int N) {
    __shared__ float s[32][33];
    int z = blockIdx.z;
    src += (size_t)z * K * N;
    dst += (size_t)z * K * N;
    int k0 = blockIdx.y * 32, n0 = blockIdx.x * 32;
    int t = threadIdx.x, r = t >> 3, c4 = (t & 7) * 4;
    float4 v = *(const float4*)&src[(size_t)(k0 + r) * N + n0 + c4];
    s[r][c4 + 0] = v.x; s[r][c4 + 1] = v.y; s[r][c4 + 2] = v.z; s[r][c4 + 3] = v.w;
    __syncthreads();
    ushort4 o;
    o.x = to_bf(s[c4 + 0][r]); o.y = to_bf(s[c4 + 1][r]);
    o.z = to_bf(s[c4 + 2][r]); o.w = to_bf(s[c4 + 3][r]);
    *(ushort4*)&dst[(size_t)(n0 + r) * K + k0 + c4] = o;
}

// all-layer w1/w2 transpose-convert with 16-col interleaved packing
__global__ __launch_bounds__(256) void k_wcvtT12L(const float* __restrict__ w1,
                                                  const float* __restrict__ w2,
                                                  u16* __restrict__ w12All) {
    __shared__ float s[32][33];
    int z = blockIdx.z;
    int layer = z >> 1, sel = z & 1;
    const float* src = (sel ? w2 : w1) + (size_t)layer * 1048576;
    u16* dst = w12All + (size_t)layer * 2097152;
    int k0 = blockIdx.y * 32, n0 = blockIdx.x * 32;
    int t = threadIdx.x, r = t >> 3, c4 = (t & 7) * 4;
    float4 v = *(const float4*)&src[(size_t)(k0 + r) * 2048 + n0 + c4];
    s[r][c4 + 0] = v.x; s[r][c4 + 1] = v.y; s[r][c4 + 2] = v.z; s[r][c4 + 3] = v.w;
    __syncthreads();
    ushort4 o;
    o.x = to_bf(s[c4 + 0][r]); o.y = to_bf(s[c4 + 1][r]);
    o.z = to_bf(s[c4 + 2][r]); o.w = to_bf(s[c4 + 3][r]);
    int nsrc = n0 + r;
    int p = ((nsrc >> 4) << 5) + (sel << 4) + (nsrc & 15);
    *(ushort4*)&dst[(size_t)p * 512 + k0 + c4] = o;
}

// ---------------- conv1: fp32 direct, bf16 NHWC out + GN partial sums ----------------
__global__ __launch_bounds__(256) void k_conv1(const float* __restrict__ in,
                                               const float* __restrict__ wt,   // [27][32]
                                               const float* __restrict__ bias,
                                               u16* __restrict__ f1n,
                                               float* __restrict__ sacc) {
    __shared__ float s_in[3][18][18];
    __shared__ float rs[4][4], rq[4][4];
    int b = blockIdx.y;
    int tile = blockIdx.x;
    int y0 = (tile >> 3) << 4;
    int x0 = (tile & 7) << 4;
    int tid = threadIdx.x;
    for (int idx = tid; idx < 972; idx += 256) {
        int ci = idx / 324, r = idx % 324;
        int ly = r / 18, lx = r % 18;
        int gy = y0 + ly - 1, gx = x0 + lx - 1;
        float v = 0.0f;
        if (gy >= 0 && gy < 128 && gx >= 0 && gx < 128)
            v = in[((size_t)(b * 3 + ci) * 128 + gy) * 128 + gx];
        s_in[ci][ly][lx] = v;
    }
    __syncthreads();
    int py = tid >> 4, px = tid & 15;
    float acc[32];
#pragma unroll
    for (int co = 0; co < 32; co++) acc[co] = bias[co];
#pragma unroll
    for (int ci = 0; ci < 3; ci++)
#pragma unroll
        for (int dy = 0; dy < 3; dy++)
#pragma unroll
            for (int dx = 0; dx < 3; dx++) {
                float v = s_in[ci][py + dy][px + dx];
                const float* wr = &wt[(ci * 9 + dy * 3 + dx) * 32];
#pragma unroll
                for (int co = 0; co < 32; co++)
                    acc[co] = fmaf(wr[co], v, acc[co]);
            }
    float s[4] = {0.f, 0.f, 0.f, 0.f}, q[4] = {0.f, 0.f, 0.f, 0.f};
    u16 ob[32];
#pragma unroll
    for (int co = 0; co < 32; co++) {
        u16 hv = to_bf(acc[co]);
        ob[co] = hv;
        float v = to_f(hv);
        s[co >> 3] += v;
        q[co >> 3] += v * v;
    }
    int oy = y0 + py, ox = x0 + px;
    u16* dst = f1n + ((size_t)(b * 16384 + oy * 128 + ox) << 5);
#pragma unroll
    for (int i = 0; i < 8; i++)
        *(ushort4*)(dst + i * 4) = make_ushort4(ob[i * 4], ob[i * 4 + 1], ob[i * 4 + 2], ob[i * 4 + 3]);
#pragma unroll
    for (int g = 0; g < 4; g++) {
#pragma unroll
        for (int off = 1; off < 64; off <<= 1) {
            s[g] += __shfl_xor(s[g], off);
            q[g] += __shfl_xor(q[g], off);
        }
    }
    int w = tid >> 6, lane = tid & 63;
    if (lane == 0)
#pragma unroll
        for (int g = 0; g < 4; g++) { rs[g][w] = s[g]; rq[g][w] = q[g]; }
    __syncthreads();
    if (tid < 4) {
        int g = tid;
        float S = rs[g][0] + rs[g][1] + rs[g][2] + rs[g][3];
        float Q = rq[g][0] + rq[g][1] + rq[g][2] + rq[g][3];
        atomicAdd(&sacc[(b * 4 + g) * 2], S);
        atomicAdd(&sacc[(b * 4 + g) * 2 + 1], Q);
    }
}

// GN apply + GELU, bf16 NHWC in-place; stats finalized inline from sacc
__global__ void k_gnap(u16* __restrict__ xio, const float* __restrict__ sacc,
                       const float* __restrict__ gg, const float* __restrict__ bb,
                       int cm, int sh, int gmul) {
    int idx = blockIdx.x * 256 + threadIdx.x;
    long e = (long)idx * 4;
    int c0 = (int)(e & cm);
    int b = (int)(e >> sh);
    int sid = b * gmul + (c0 >> 3);
    float m = sacc[2 * sid] * (1.0f / 131072.0f);
    float var = sacc[2 * sid + 1] * (1.0f / 131072.0f) - m * m;
    float r = rsqrtf(var + 1e-5f);
    ushort4 a = *(ushort4*)&xio[e];
    ushort4 o;
    o.x = to_bf(gelu_exact((to_f(a.x) - m) * r * gg[c0 + 0] + bb[c0 + 0]));
    o.y = to_bf(gelu_exact((to_f(a.y) - m) * r * gg[c0 + 1] + bb[c0 + 1]));
    o.z = to_bf(gelu_exact((to_f(a.z) - m) * r * gg[c0 + 2] + bb[c0 + 2]));
    o.w = to_bf(gelu_exact((to_f(a.w) - m) * r * gg[c0 + 3] + bb[c0 + 3]));
    *(ushort4*)&xio[e] = o;
}

// ---------------- conv2 MFMA implicit GEMM, zero-LDS input, LDS-transposed coalesced epilogue ----------------
__global__ __launch_bounds__(256) void k_conv2m(const u16* __restrict__ f1b,
                                                const u16* __restrict__ wp,   // [9][64][32]
                                                const float* __restrict__ bias,
                                                u16* __restrict__ f2n,
                                                float* __restrict__ sacc) {
    __shared__ u16 st[256][72];
    __shared__ float rs[8][4], rq[8][4];
    int b = blockIdx.y;
    int tile = blockIdx.x;
    int y0 = (tile >> 3) << 4;
    int x0 = (tile & 7) << 4;
    int tid = threadIdx.x;
    int w = tid >> 6, lane = tid & 63;
    int l15 = lane & 15, l16 = lane >> 4;

    const u16* base = f1b + ((size_t)b << 19);

    f32x4 acc[4][4];
    f32x4 zf = {0.f, 0.f, 0.f, 0.f};
#pragma unroll
    for (int m = 0; m < 4; m++)
#pragma unroll
        for (int n = 0; n < 4; n++) acc[m][n] = zf;
    bf16x8 zb = {0, 0, 0, 0, 0, 0, 0, 0};

#pragma unroll
    for (int tap = 0; tap < 9; tap++) {
        int dy = tap / 3, dx = tap % 3;
        int gx = x0 + l15 + dx - 1;
        bf16x8 af[4], bk[4];
#pragma unroll
        for (int m = 0; m < 4; m++) {
            int gy = y0 + w * 4 + m + dy - 1;
            bool ok = (gy >= 0) && (gy < 128) && (gx >= 0) && (gx < 128);
            int pix = ok ? (gy * 128 + gx) : 0;
            bf16x8 v = *(const bf16x8*)(base + ((size_t)pix << 5) + l16 * 8);
            af[m] = ok ? v : zb;
        }
#pragma unroll
        for (int n = 0; n < 4; n++)
            bk[n] = *(const bf16x8*)&wp[(tap * 64 + n * 16 + l15) * 32 + l16 * 8];
#pragma unroll
        for (int m = 0; m < 4; m++)
#pragma unroll
            for (int n = 0; n < 4; n++)
                acc[m][n] = __builtin_amdgcn_mfma_f32_16x16x32_bf16(af[m], bk[n], acc[m][n], 0, 0, 0);
    }

#pragma unroll
    for (int n = 0; n < 4; n++) {
        int ch = n * 16 + l15;
        float bv = bias[ch];
#pragma unroll
        for (int m = 0; m < 4; m++) {
#pragma unroll
            for (int r = 0; r < 4; r++) {
                int lpix = (w * 4 + m) * 16 + l16 * 4 + r;
                st[lpix][ch] = to_bf(acc[m][n][r] + bv);
            }
        }
    }
    __syncthreads();

    int py = tid >> 4, pxx = tid & 15;
    u16* dstp = f2n + ((size_t)(b * 16384 + (y0 + py) * 128 + x0 + pxx) << 6);
    float gs[8], gq[8];
#pragma unroll
    for (int g = 0; g < 8; g++) { gs[g] = 0.0f; gq[g] = 0.0f; }
#pragma unroll
    for (int c0 = 0; c0 < 8; c0++) {
        u16x8 v = *(const u16x8*)&st[tid][c0 * 8];
        *(u16x8*)(dstp + c0 * 8) = v;
#pragma unroll
        for (int i = 0; i < 8; i++) {
            float f = to_f((u16)v[i]);
            gs[c0] += f;
            gq[c0] += f * f;
        }
    }
#pragma unroll
    for (int g = 0; g < 8; g++) {
#pragma unroll
        for (int off = 1; off < 64; off <<= 1) {
            gs[g] += __shfl_xor(gs[g], off);
            gq[g] += __shfl_xor(gq[g], off);
        }
    }
    if (lane == 0)
#pragma unroll
        for (int g = 0; g < 8; g++) { rs[g][w] = gs[g]; rq[g][w] = gq[g]; }
    __syncthreads();
    if (tid < 8) {
        int g = tid;
        float S = rs[g][0] + rs[g][1] + rs[g][2] + rs[g][3];
        float Q = rq[g][0] + rq[g][1] + rq[g][2] + rq[g][3];
        atomicAdd(&sacc[(b * 8 + g) * 2], S);
        atomicAdd(&sacc[(b * 8 + g) * 2 + 1], Q);
    }
}

// ---------------- bf16 MFMA GEMM (128x128), single-buffer, 2-D grid (R11 variant) ----------------
// MODE 0: A [M,K]. MODE 1: implicit im2col of f2n NHWC.
// EPI 1: fp32 C = acc+bias. EPI 2: fp32 C += acc+bias. EPI 3: patch scatter + postab.
// EPI 7: bf16 C = rope(acc+bias) for cols<1024, else acc+bias.
template <int MODE, int EPI>
__global__ __launch_bounds__(256) void k_bgemm(const u16* __restrict__ A,
                                               const u16* __restrict__ Bt,
                                               const float* __restrict__ bias,
                                               void* __restrict__ Cp,
                                               const float* __restrict__ aux,
                                               int M, int N, int K) {
    __shared__ u16 ldsA[8192];
    __shared__ u16 ldsB[8192];
    int tid = threadIdx.x;
    int w = tid >> 6, lane = tid & 63;
    int bm = blockIdx.y * 128, bn = blockIdx.x * 128;
    int wr = w >> 1, wc = w & 1;
    int l15 = lane & 15, l16 = lane >> 4;

    f32x4 acc[4][4];
    f32x4 zf = {0.f, 0.f, 0.f, 0.f};
#pragma unroll
    for (int m = 0; m < 4; m++)
#pragma unroll
        for (int n = 0; n < 4; n++) acc[m][n] = zf;

    for (int k0 = 0; k0 < K; k0 += 64) {
#pragma unroll
        for (int i = 0; i < 4; i++) {
            int chunk = (w * 4 + i) * 64 + lane;
            int kg = chunk >> 7, row = chunk & 127;
            const u16* src;
            if (MODE == 0) {
                int grow = bm + row;
                if (grow > M - 1) grow = M - 1;
                src = A + (size_t)grow * K + k0 + kg * 8;
            } else {
                int grow = bm + row;
                int bimg = grow >> 8, p = grow & 255;
                int kga = (k0 >> 3) + kg;
                int tap = kga >> 3, cq = kga & 7;
                int ky = tap >> 3, kx = tap & 7;
                int gy = ((p >> 4) << 3) + ky, gx = ((p & 15) << 3) + kx;
                src = A + (((size_t)(bimg * 16384 + gy * 128 + gx)) << 6) + cq * 8;
            }
            gload_lds16(src, &ldsA[(w * 4 + i) * 512]);
        }
#pragma unroll
        for (int i = 0; i < 4; i++) {
            int chunk = (w * 4 + i) * 64 + lane;
            int col = chunk >> 3, kgs = chunk & 7;
            int kg_src = kgs ^ (col & 7);
            const u16* src = Bt + (size_t)(bn + col) * K + k0 + kg_src * 8;
            gload_lds16(src, &ldsB[(w * 4 + i) * 512]);
        }
        __syncthreads();

        bf16x8 af[4][2], bfr[4][2];
#pragma unroll
        for (int kk = 0; kk < 2; kk++) {
            int kga = kk * 4 + l16;
#pragma unroll
            for (int m = 0; m < 4; m++) {
                int row_l = wr * 64 + m * 16 + l15;
                af[m][kk] = *(const bf16x8*)&ldsA[(kga * 128 + row_l) * 8];
            }
#pragma unroll
            for (int n = 0; n < 4; n++) {
                int col_l = wc * 64 + n * 16 + l15;
                bfr[n][kk] = *(const bf16x8*)&ldsB[(col_l * 8 + (kga ^ (col_l & 7))) * 8];
            }
        }
#pragma unroll
        for (int m = 0; m < 4; m++)
#pragma unroll
            for (int n = 0; n < 4; n++) {
                acc[m][n] = __builtin_amdgcn_mfma_f32_16x16x32_bf16(af[m][0], bfr[n][0], acc[m][n], 0, 0, 0);
                acc[m][n] = __builtin_amdgcn_mfma_f32_16x16x32_bf16(af[m][1], bfr[n][1], acc[m][n], 0, 0, 0);
            }
        __syncthreads();
    }

#pragma unroll
    for (int n = 0; n < 4; n++) {
        int gcol = bn + wc * 64 + n * 16 + l15;
        float bv = bias[gcol];
        float rc = 0.f, rsn = 0.f, rsc = 1.f;
        bool isqk = false, odd = false;
        if (EPI == 7) {
            isqk = gcol < 1024;
            odd = (l15 & 1) != 0;
            const float* rb = &aux[(gcol & 511) * 4];
            if (isqk) {
                rc = rb[0]; rsn = rb[1];
                rsc = (gcol < 512) ? rb[2] : rb[3];
            }
        }
#pragma unroll
        for (int m = 0; m < 4; m++) {
#pragma unroll
            for (int r = 0; r < 4; r++) {
                int grow = bm + wr * 64 + m * 16 + l16 * 4 + r;
                float v = acc[m][n][r] + bv;
                if (EPI == 7) {
                    float p = __shfl_xor(v, 1);
                    float vr = isqk ? ((odd ? (v * rc + p * rsn) : (v * rc - p * rsn)) * rsc) : v;
                    if (grow < M) ((u16*)Cp)[(size_t)grow * N + gcol] = to_bf(vr);
                } else if (EPI == 1) {
                    if (grow < M) ((float*)Cp)[(size_t)grow * N + gcol] = v;
                } else if (EPI == 2) {
                    if (grow < M) ((float*)Cp)[(size_t)grow * N + gcol] += v;
                } else {
                    int bimg = grow >> 8, p2 = grow & 255;
                    v += aux[p2 * 512 + gcol];
                    ((float*)Cp)[((size_t)(bimg * 257) + 1 + p2) * 512 + gcol] = v;
                }
            }
        }
    }
}

// ---------------- w12 GEMM: 2-phase double-buffered + XCD swizzle, EPI6 swiglu (R13 variant) ----------------
__global__ __launch_bounds__(256) void k_bgemm_db(const u16* __restrict__ A,
                                                  const u16* __restrict__ Bt,
                                                  const float* __restrict__ bias,
                                                  u16* __restrict__ Cp,
                                                  int M, int N, int K, int gridN) {
    __shared__ u16 ldsA[2][8192];
    __shared__ u16 ldsB[2][8192];
    int tid = threadIdx.x;
    int w = tid >> 6, lane = tid & 63;
    int wgid = xcd_swz();
    int bm = (wgid / gridN) * 128, bn = (wgid % gridN) * 128;
    int wr = w >> 1, wc = w & 1;
    int l15 = lane & 15, l16 = lane >> 4;

    auto stage = [&](int k0, int bb) {
#pragma unroll
        for (int i = 0; i < 4; i++) {
            int chunk = (w * 4 + i) * 64 + lane;
            int kg = chunk >> 7, row = chunk & 127;
            int grow = bm + row;
            if (grow > M - 1) grow = M - 1;
            const u16* src = A + (size_t)grow * K + k0 + kg * 8;
            gload_lds16(src, &ldsA[bb][(w * 4 + i) * 512]);
        }
#pragma unroll
        for (int i = 0; i < 4; i++) {
            int chunk = (w * 4 + i) * 64 + lane;
            int col = chunk >> 3, kgs = chunk & 7;
            int kg_src = kgs ^ (col & 7);
            const u16* src = Bt + (size_t)(bn + col) * K + k0 + kg_src * 8;
            gload_lds16(src, &ldsB[bb][(w * 4 + i) * 512]);
        }
    };

    f32x4 acc[4][4];
    f32x4 zf = {0.f, 0.f, 0.f, 0.f};
#pragma unroll
    for (int m = 0; m < 4; m++)
#pragma unroll
        for (int n = 0; n < 4; n++) acc[m][n] = zf;

    int nk = K >> 6;
    stage(0, 0);
    __syncthreads();
    int cur = 0;
    for (int kt = 0; kt < nk; kt++) {
        if (kt + 1 < nk) stage((kt + 1) << 6, cur ^ 1);

        bf16x8 af[4][2], bfr[4][2];
#pragma unroll
        for (int kk = 0; kk < 2; kk++) {
            int kga = kk * 4 + l16;
#pragma unroll
            for (int m = 0; m < 4; m++) {
                int row_l = wr * 64 + m * 16 + l15;
                af[m][kk] = *(const bf16x8*)&ldsA[cur][(kga * 128 + row_l) * 8];
            }
#pragma unroll
            for (int n = 0; n < 4; n++) {
                int col_l = wc * 64 + n * 16 + l15;
                bfr[n][kk] = *(const bf16x8*)&ldsB[cur][(col_l * 8 + (kga ^ (col_l & 7))) * 8];
            }
        }
#pragma unroll
        for (int m = 0; m < 4; m++)
#pragma unroll
            for (int n = 0; n < 4; n++) {
                acc[m][n] = __builtin_amdgcn_mfma_f32_16x16x32_bf16(af[m][0], bfr[n][0], acc[m][n], 0, 0, 0);
                acc[m][n] = __builtin_amdgcn_mfma_f32_16x16x32_bf16(af[m][1], bfr[n][1], acc[m][n], 0, 0, 0);
            }
        __syncthreads();
        cur ^= 1;
    }

#pragma unroll
    for (int np = 0; np < 2; np++) {
        int n_a = np * 2, n_b = np * 2 + 1;
        float bva = bias[bn + wc * 64 + n_a * 16 + l15];
        float bvb = bias[bn + wc * 64 + n_b * 16 + l15];
        int ocol = (bn >> 1) + wc * 32 + np * 16 + l15;
#pragma unroll
        for (int m = 0; m < 4; m++) {
#pragma unroll
            for (int r = 0; r < 4; r++) {
                int grow = bm + wr * 64 + m * 16 + l16 * 4 + r;
                if (grow < M) {
                    float h1v = to_f(to_bf(acc[m][n_a][r] + bva));
                    float h2v = to_f(to_bf(acc[m][n_b][r] + bvb));
                    float sl = h1v / (1.0f + __expf(-h1v));
                    Cp[(size_t)grow * (N >> 1) + ocol] = to_bf(sl * h2v);
                }
            }
        }
    }
}

// ---------------- bf16 MFMA GEMM, BM=64 x BN=128, single-buffer, 2-D grid (EPI2, R11 variant) ----------------
__global__ __launch_bounds__(256) void k_bgemm64(const u16* __restrict__ A,
                                                 const u16* __restrict__ Bt,
                                                 const float* __restrict__ bias,
                                                 float* __restrict__ C,
                                                 int M, int N, int K) {
    __shared__ u16 ldsA[4096];
    __shared__ u16 ldsB[8192];
    int tid = threadIdx.x;
    int w = tid >> 6, lane = tid & 63;
    int bm = blockIdx.y * 64, bn = blockIdx.x * 128;
    int l15 = lane & 15, l16 = lane >> 4;

    f32x4 acc[4][2];
    f32x4 zf = {0.f, 0.f, 0.f, 0.f};
#pragma unroll
    for (int m = 0; m < 4; m++)
#pragma unroll
        for (int n = 0; n < 2; n++) acc[m][n] = zf;

    for (int k0 = 0; k0 < K; k0 += 64) {
#pragma unroll
        for (int i = 0; i < 2; i++) {
            int chunk = (w * 2 + i) * 64 + lane;
            int kg = chunk >> 6, row = chunk & 63;
            int grow = bm + row;
            if (grow > M - 1) grow = M - 1;
            const u16* src = A + (size_t)grow * K + k0 + kg * 8;
            gload_lds16(src, &ldsA[(w * 2 + i) * 512]);
        }
#pragma unroll
        for (int i = 0; i < 4; i++) {
            int chunk = (w * 4 + i) * 64 + lane;
            int col = chunk >> 3, kgs = chunk & 7;
            int kg_src = kgs ^ (col & 7);
            const u16* src = Bt + (size_t)(bn + col) * K + k0 + kg_src * 8;
            gload_lds16(src, &ldsB[(w * 4 + i) * 512]);
        }
        __syncthreads();

        bf16x8 af[4][2], bfr[2][2];
#pragma unroll
        for (int kk = 0; kk < 2; kk++) {
            int kga = kk * 4 + l16;
#pragma unroll
            for (int m = 0; m < 4; m++) {
                int row_l = m * 16 + l15;
                af[m][kk] = *(const bf16x8*)&ldsA[(kga * 64 + row_l) * 8];
            }
#pragma unroll
            for (int n = 0; n < 2; n++) {
                int col_l = w * 32 + n * 16 + l15;
                bfr[n][kk] = *(const bf16x8*)&ldsB[(col_l * 8 + (kga ^ (col_l & 7))) * 8];
            }
        }
#pragma unroll
        for (int m = 0; m < 4; m++)
#pragma unroll
            for (int n = 0; n < 2; n++) {
                acc[m][n] = __builtin_amdgcn_mfma_f32_16x16x32_bf16(af[m][0], bfr[n][0], acc[m][n], 0, 0, 0);
                acc[m][n] = __builtin_amdgcn_mfma_f32_16x16x32_bf16(af[m][1], bfr[n][1], acc[m][n], 0, 0, 0);
            }
        __syncthreads();
    }

#pragma unroll
    for (int n = 0; n < 2; n++) {
        int gcol = bn + w * 32 + n * 16 + l15;
        float bv = bias[gcol];
#pragma unroll
        for (int m = 0; m < 4; m++) {
#pragma unroll
            for (int r = 0; r < 4; r++) {
                int grow = bm + m * 16 + l16 * 4 + r;
                if (grow < M) C[(size_t)grow * N + gcol] += acc[m][n][r] + bv;
            }
        }
    }
}

// ---------------- LayerNorm, wave-per-row, bf16 out ----------------
__global__ __launch_bounds__(256) void k_lnb(const float* __restrict__ x,
                                             const float* __restrict__ g,
                                             const float* __restrict__ bta,
                                             u16* __restrict__ o) {
    int row = blockIdx.x * 4 + (threadIdx.x >> 6);
    int lane = threadIdx.x & 63;
    const float4* xr = (const float4*)(x + (size_t)row * 512);
    float4 a = xr[lane * 2], b = xr[lane * 2 + 1];
    float s = a.x + a.y + a.z + a.w + b.x + b.y + b.z + b.w;
#pragma unroll
    for (int off = 1; off < 64; off <<= 1) s += __shfl_xor(s, off);
    float mean = s * (1.0f / 512.0f);
    float d[8] = {a.x - mean, a.y - mean, a.z - mean, a.w - mean,
                  b.x - mean, b.y - mean, b.z - mean, b.w - mean};
    float q = 0.0f;
#pragma unroll
    for (int i = 0; i < 8; i++) q += d[i] * d[i];
#pragma unroll
    for (int off = 1; off < 64; off <<= 1) q += __shfl_xor(q, off);
    float rstd = rsqrtf(q * (1.0f / 512.0f) + EPSV);
    int c0 = lane * 8;
    float4 g0 = *(const float4*)&g[c0], g1 = *(const float4*)&g[c0 + 4];
    float4 b0 = *(const float4*)&bta[c0], b1 = *(const float4*)&bta[c0 + 4];
    u16* orow = o + (size_t)row * 512 + c0;
    *(ushort4*)orow = make_ushort4(to_bf(d[0] * rstd * g0.x + b0.x), to_bf(d[1] * rstd * g0.y + b0.y),
                                   to_bf(d[2] * rstd * g0.z + b0.z), to_bf(d[3] * rstd * g0.w + b0.w));
    *(ushort4*)(orow + 4) = make_ushort4(to_bf(d[4] * rstd * g1.x + b1.x), to_bf(d[5] * rstd * g1.y + b1.y),
                                         to_bf(d[6] * rstd * g1.z + b1.z), to_bf(d[7] * rstd * g1.w + b1.w));
}

// final LN, wave-per-row, output remap (fp32 out)
__global__ __launch_bounds__(256) void k_ln_out(const float* __restrict__ x,
                                                const float* __restrict__ g,
                                                const float* __restrict__ bta,
                                                float* __restrict__ out) {
    int row = blockIdx.x * 4 + (threadIdx.x >> 6);
    int lane = threadIdx.x & 63;
    const float4* xr = (const float4*)(x + (size_t)row * 512);
    float4 a = xr[lane * 2], b = xr[lane * 2 + 1];
    float s = a.x + a.y + a.z + a.w + b.x + b.y + b.z + b.w;
#pragma unroll
    for (int off = 1; off < 64; off <<= 1) s += __shfl_xor(s, off);
    float mean = s * (1.0f / 512.0f);
    float d[8] = {a.x - mean, a.y - mean, a.z - mean, a.w - mean,
                  b.x - mean, b.y - mean, b.z - mean, b.w - mean};
    float q = 0.0f;
#pragma unroll
    for (int i = 0; i < 8; i++) q += d[i] * d[i];
#pragma unroll
    for (int off = 1; off < 64; off <<= 1) q += __shfl_xor(q, off);
    float rstd = rsqrtf(q * (1.0f / 512.0f) + EPSV);
    int bb = row / 257, t = row % 257;
    float* dst = (t == 0) ? out + (size_t)bb * 512
                          : out + 16384 + (size_t)(bb * 256 + (t - 1)) * 512;
    int c0 = lane * 8;
    float4 g0 = *(const float4*)&g[c0], g1 = *(const float4*)&g[c0 + 4];
    float4 b0 = *(const float4*)&bta[c0], b1 = *(const float4*)&bta[c0 + 4];
    *(float4*)(dst + c0) = make_float4(d[0] * rstd * g0.x + b0.x, d[1] * rstd * g0.y + b0.y,
                                       d[2] * rstd * g0.z + b0.z, d[3] * rstd * g0.w + b0.w);
    *(float4*)(dst + c0 + 4) = make_float4(d[4] * rstd * g1.x + b1.x, d[5] * rstd * g1.y + b1.y,
                                           d[6] * rstd * g1.z + b1.z, d[7] * rstd * g1.w + b1.w);
}

// ---------------- MFMA attention: pre-roped qkv, direct-global Q/K, dbuf PV, setprio ----------------
__global__ __launch_bounds__(256) void k_attn_mfma(const u16* __restrict__ qkv,
                                                   u16* __restrict__ y) {
    __shared__ u16 KV[2][64][72];
    __shared__ float sc[32][260];
    __shared__ u16 Pb[32][328];
    __shared__ float red1[32][8];
    __shared__ float red2[32][8];
    __shared__ float invr[32];

    int bid = blockIdx.x;                 // ((b*8+h)*9 + qt)
    int qt = bid % 9, bh = bid / 9;
    int h = bh & 7, b = bh >> 3;
    int q0 = qt * 32;
    int tid = threadIdx.x;
    int w = tid >> 6, lane = tid & 63;
    int l15 = lane & 15, l16 = lane >> 4;

    bf16x8 aq[2][2];
#pragma unroll
    for (int m = 0; m < 2; m++) {
        int grow = q0 + m * 16 + l15; if (grow > 256) grow = 256;
        const u16* qp = qkv + (size_t)(b * 257 + grow) * 1536 + h * 64 + l16 * 8;
        aq[m][0] = *(const bf16x8*)qp;
        aq[m][1] = *(const bf16x8*)(qp + 32);
    }

    for (int t = 0; t < 5; t++) {
        int j0 = t * 64;
        int gk = j0 + w * 16 + l15; if (gk > 256) gk = 256;
        const u16* kp = qkv + (size_t)(b * 257 + gk) * 1536 + 512 + h * 64 + l16 * 8;
        bf16x8 bk0 = *(const bf16x8*)kp;
        bf16x8 bk1 = *(const bf16x8*)(kp + 32);
        f32x4 a2[2];
        f32x4 zf = {0.f, 0.f, 0.f, 0.f};
        __builtin_amdgcn_s_setprio(1);
#pragma unroll
        for (int m = 0; m < 2; m++) {
            a2[m] = zf;
            a2[m] = __builtin_amdgcn_mfma_f32_16x16x32_bf16(aq[m][0], bk0, a2[m], 0, 0, 0);
            a2[m] = __builtin_amdgcn_mfma_f32_16x16x32_bf16(aq[m][1], bk1, a2[m], 0, 0, 0);
        }
        __builtin_amdgcn_s_setprio(0);
        int col = j0 + w * 16 + l15;
        if (col < 257) {
#pragma unroll
            for (int m = 0; m < 2; m++)
#pragma unroll
                for (int r = 0; r < 4; r++)
                    sc[m * 16 + l16 * 4 + r][col] = a2[m][r];
        }
    }
    __syncthreads();

    {
        int r = tid >> 3, sub = tid & 7;
        float mx = -1e30f;
        for (int j = sub; j < 257; j += 8) mx = fmaxf(mx, sc[r][j]);
        red1[r][sub] = mx;
        __syncthreads();
        mx = red1[r][0];
#pragma unroll
        for (int i = 1; i < 8; i++) mx = fmaxf(mx, red1[r][i]);
        float sm = 0.0f;
        for (int j = sub; j < 257; j += 8) {
            float e = __expf(sc[r][j] - mx);
            Pb[r][j] = to_bf(e);
            sm += e;
        }
        for (int j = 257 + sub; j < 320; j += 8) Pb[r][j] = 0;
        red2[r][sub] = sm;
        __syncthreads();
        if (sub == 0) {
            float t = red2[r][0];
#pragma unroll
            for (int i = 1; i < 8; i++) t += red2[r][i];
            invr[r] = 1.0f / t;
        }
        __syncthreads();
    }

    f32x4 oacc[2];
    {
        f32x4 zf = {0.f, 0.f, 0.f, 0.f};
        oacc[0] = zf; oacc[1] = zf;
    }
    for (int t = 0; t < 5; t++) {
        int j0 = t * 64;
        int buf = t & 1;
        {
            int vk = tid & 63, vd0 = (tid >> 6) * 16;
            int gk = j0 + vk;
            u16 o[16];
            if (gk <= 256) {
                const u16* vp = qkv + (size_t)(b * 257 + gk) * 1536 + 1024 + h * 64 + vd0;
                ushort4 a0 = *(const ushort4*)vp, a1 = *(const ushort4*)(vp + 4);
                ushort4 a2v = *(const ushort4*)(vp + 8), a3 = *(const ushort4*)(vp + 12);
                o[0] = a0.x; o[1] = a0.y; o[2] = a0.z; o[3] = a0.w;
                o[4] = a1.x; o[5] = a1.y; o[6] = a1.z; o[7] = a1.w;
                o[8] = a2v.x; o[9] = a2v.y; o[10] = a2v.z; o[11] = a2v.w;
                o[12] = a3.x; o[13] = a3.y; o[14] = a3.z; o[15] = a3.w;
            } else {
#pragma unroll
                for (int i = 0; i < 16; i++) o[i] = 0;
            }
#pragma unroll
            for (int i = 0; i < 16; i++) KV[buf][vd0 + i][vk] = o[i];
        }
        __syncthreads();

        bf16x8 ap[2][2], bv[2];
#pragma unroll
        for (int m = 0; m < 2; m++)
#pragma unroll
            for (int kk = 0; kk < 2; kk++)
                ap[m][kk] = *(const bf16x8*)&Pb[m * 16 + l15][j0 + kk * 32 + l16 * 8];
#pragma unroll
        for (int kk = 0; kk < 2; kk++)
            bv[kk] = *(const bf16x8*)&KV[buf][w * 16 + l15][kk * 32 + l16 * 8];
        __builtin_amdgcn_s_setprio(1);
#pragma unroll
        for (int m = 0; m < 2; m++) {
            oacc[m] = __builtin_amdgcn_mfma_f32_16x16x32_bf16(ap[m][0], bv[0], oacc[m], 0, 0, 0);
            oacc[m] = __builtin_amdgcn_mfma_f32_16x16x32_bf16(ap[m][1], bv[1], oacc[m], 0, 0, 0);
        }
        __builtin_amdgcn_s_setprio(0);
    }

#pragma unroll
    for (int m = 0; m < 2; m++)
#pragma unroll
        for (int r = 0; r < 4; r++) {
            int lr = m * 16 + l16 * 4 + r;
            int grow = q0 + lr;
            if (grow < 257)
                y[(size_t)(b * 257 + grow) * 512 + h * 64 + w * 16 + l15] =
                    to_bf(oacc[m][r] * invr[lr]);
        }
}

// ---------------- host launch ----------------
extern "C" void kernel_launch(void* const* d_in, const int* in_sizes, int n_in,
                              void* d_out, int out_size, void* d_ws, size_t ws_size,
                              hipStream_t stream) {
    const float* x       = (const float*)d_in[0];
    const float* conv1_w = (const float*)d_in[1];
    const float* conv1_b = (const float*)d_in[2];
    const float* gn1_g   = (const float*)d_in[3];
    const float* gn1_b   = (const float*)d_in[4];
    const float* conv2_w = (const float*)d_in[5];
    const float* conv2_b = (const float*)d_in[6];
    const float* gn2_g   = (const float*)d_in[7];
    const float* gn2_b   = (const float*)d_in[8];
    const float* patch_w = (const float*)d_in[9];
    const float* patch_b = (const float*)d_in[10];
    const float* cls_tok = (const float*)d_in[11];
    const float* ln1_g   = (const float*)d_in[12];
    const float* ln1_b   = (const float*)d_in[13];
    const float* qkv_w   = (const float*)d_in[14];
    const float* qkv_b   = (const float*)d_in[15];
    const float* out_w   = (const float*)d_in[16];
    const float* out_b   = (const float*)d_in[17];
    const float* ln2_g   = (const float*)d_in[18];
    const float* ln2_b   = (const float*)d_in[19];
    const float* w1_w    = (const float*)d_in[20];
    const float* w1_b    = (const float*)d_in[21];
    const float* w2_w    = (const float*)d_in[22];
    const float* w2_b    = (const float*)d_in[23];
    const float* w3_w    = (const float*)d_in[24];
    const float* w3_b    = (const float*)d_in[25];
    const float* fn_g    = (const float*)d_in[26];
    const float* fn_b    = (const float*)d_in[27];
    float* out = (float*)d_out;
    char* wsb  = (char*)d_ws;

    const size_t O_R1    = 0;
    const size_t O_W12A  = 0;
    const size_t O_W3A   = 33554432;
    const size_t O_HB    = O_R1 + 67371008;
    const size_t O_NB    = O_R1 + 101056512;
    const size_t O_Y     = O_R1 + 109477888;
    const size_t O_R2    = 134217728;
    const size_t O_XA    = 201326592;
    const size_t O_PWT   = 218169344;
    const size_t O_QKVT  = 222363648;
    const size_t O_OUTT  = 234946560;
    const size_t O_PT    = 245432320;
    const size_t O_RT    = 245956608;
    const size_t O_CW1   = 245964800;
    const size_t O_CW2   = 245968896;
    const size_t O_SA    = 246046720;
    const size_t O_B12   = 246050816;
    const size_t NEED    = 246181888;
    if (ws_size < NEED) {
        k_wsfail<<<1, 1, 0, stream>>>(out);
        return;
    }
    u16*   f2n    = (u16*)(wsb + O_R1);
    u16*   w12All = (u16*)(wsb + O_W12A);
    u16*   w3All  = (u16*)(wsb + O_W3A);
    u16*   hb     = (u16*)(wsb + O_HB);
    u16*   nb     = (u16*)(wsb + O_NB);
    u16*   yb     = (u16*)(wsb + O_Y);
    u16*   f1n    = (u16*)(wsb + O_R2);
    u16*   qkvb   = (u16*)(wsb + O_R2);
    float* xa     = (float*)(wsb + O_XA);
    u16*   patchT = (u16*)(wsb + O_PWT);
    u16*   qkvT   = (u16*)(wsb + O_QKVT);
    u16*   outT   = (u16*)(wsb + O_OUTT);
    float* postab = (float*)(wsb + O_PT);
    float* ropet  = (float*)(wsb + O_RT);
    float* w1t    = (float*)(wsb + O_CW1);
    u16*   wpack  = (u16*)(wsb + O_CW2);
    float* sacc   = (float*)(wsb + O_SA);
    float* bias12 = (float*)(wsb + O_B12);

    // setup + persistent weight conversions
    k_setup<<<512, 256, 0, stream>>>(sacc, conv1_w, w1t, conv2_w, wpack,
                                     w1_b, w2_b, bias12, postab, ropet, cls_tok, xa);
    k_pperm<<<8192, 256, 0, stream>>>(patch_w, patchT);
    k_wcvtT<<<dim3(48, 16, 8), 256, 0, stream>>>(qkv_w, qkvT, 512, 1536);
    k_wcvtT<<<dim3(16, 16, 8), 256, 0, stream>>>(out_w, outT, 512, 512);

    // conv stem
    k_conv1<<<dim3(64, 32), 256, 0, stream>>>(x, w1t, conv1_b, f1n, sacc);
    k_gnap<<<16384, 256, 0, stream>>>(f1n, sacc, gn1_g, gn1_b, 31, 19, 4);
    k_conv2m<<<dim3(64, 32), 256, 0, stream>>>(f1n, wpack, conv2_b, f2n, sacc + 256);
    k_gnap<<<32768, 256, 0, stream>>>(f2n, sacc + 256, gn2_g, gn2_b, 63, 20, 8);

    // patch embed (2-D grid, R11 config)
    k_bgemm<1, 3><<<dim3(4, 64), 256, 0, stream>>>(f2n, patchT, patch_b, xa, postab, 8192, 512, 4096);

    // one-time all-layer MLP weight conversion into freed region
    k_wcvtT12L<<<dim3(64, 16, 16), 256, 0, stream>>>(w1_w, w2_w, w12All);
    k_wcvtT<<<dim3(16, 64, 8), 256, 0, stream>>>(w3_w, w3All, 2048, 512);

    // transformer
    for (int l = 0; l < 8; l++) {
        k_lnb<<<2056, 256, 0, stream>>>(xa, ln1_g + l * 512, ln1_b + l * 512, nb);
        k_bgemm<0, 7><<<dim3(12, 65), 256, 0, stream>>>(nb, qkvT + (size_t)l * 786432,
                                                        qkv_b + l * 1536, qkvb, ropet, 8224, 1536, 512);
        k_attn_mfma<<<2304, 256, 0, stream>>>(qkvb, yb);
        k_bgemm64<<<dim3(4, 129), 256, 0, stream>>>(yb, outT + (size_t)l * 262144,
                                                    out_b + l * 512, xa, 8224, 512, 512);
        k_lnb<<<2056, 256, 0, stream>>>(xa, ln2_g + l * 512, ln2_b + l * 512, nb);
        k_bgemm_db<<<2080, 256, 0, stream>>>(nb, w12All + (size_t)l * 2097152,
                                             bias12 + l * 4096, hb, 8224, 4096, 512, 32);
        k_bgemm64<<<dim3(4, 129), 256, 0, stream>>>(hb, w3All + (size_t)l * 1048576,
                                                    w3_b + l * 512, xa, 8224, 512, 2048);
    }
    k_ln_out<<<2056, 256, 0, stream>>>(xa, fn_g, fn_b, out);
}

// Round 15
// 2271.878 us; speedup vs baseline: 1.0600x; 1.0600x over previous
//
#include <hip/hip_runtime.h>

#define EPSV 1e-5f
typedef unsigned short u16;
typedef short bf16x8 __attribute__((ext_vector_type(8)));
typedef float f32x4 __attribute__((ext_vector_type(4)));
typedef u16 u16x8 __attribute__((ext_vector_type(8)));

__device__ __forceinline__ float gelu_exact(float x) {
    return 0.5f * x * (1.0f + erff(x * 0.7071067811865475f));
}
__device__ __forceinline__ u16 to_bf(float x) {
    union { float f; unsigned u; } c; c.f = x;
    unsigned r = c.u + 0x7fffu + ((c.u >> 16) & 1u);
    return (u16)(r >> 16);
}
__device__ __forceinline__ float to_f(u16 h) {
    union { unsigned u; float f; } c; c.u = ((unsigned)h) << 16;
    return c.f;
}
__device__ __forceinline__ void gload_lds16(const void* g, void* l) {
    __builtin_amdgcn_global_load_lds((const __attribute__((address_space(1))) unsigned int*)g,
                                     (__attribute__((address_space(3))) unsigned int*)l, 16, 0, 0);
}

// ---------------- guard ----------------
__global__ void k_wsfail(float* out) { out[0] = 1.0e9f; }

// ---------------- combined setup ----------------
__global__ void k_setup(float* __restrict__ sacc,
                        const float* __restrict__ conv1_w, float* __restrict__ w1t,
                        const float* __restrict__ conv2_w, u16* __restrict__ wpack,
                        const float* __restrict__ b1, const float* __restrict__ b2,
                        float* __restrict__ bias12,
                        float* __restrict__ postab, float* __restrict__ ropetab,
                        const float* __restrict__ cls, float* __restrict__ xa) {
    int idx = blockIdx.x * 256 + threadIdx.x;   // 512 blocks -> 131072
    if (idx < 131072) {
        int p = idx >> 9, j = idx & 511;
        float coord = (j < 256) ? (float)(p >> 4) : (float)(p & 15);
        int jm = j & 127;
        float om = powf(10000.0f, -(float)jm / 128.0f);
        float arg = coord * om;
        postab[idx] = ((j >> 7) & 1) ? cosf(arg) : sinf(arg);
    }
    if (idx < 512) {
        // xpos tables indexed by HEAD h (reference quirk): n_pos = H = 8
        int h = idx >> 6, d = idx & 63;
        float freq = (float)h * powf(10000.0f, -(float)(d >> 1) / 32.0f);
        float sv = (2.0f * (float)(d & 31) + 25.6f) / 89.6f;
        float pw = ((float)h - 4.0f) / 512.0f;
        float sc = powf(sv, pw);
        ropetab[idx * 4 + 0] = cosf(freq);
        ropetab[idx * 4 + 1] = sinf(freq);
        ropetab[idx * 4 + 2] = sc * 0.125f;
        ropetab[idx * 4 + 3] = 1.0f / sc;
    }
    if (idx < 768) sacc[idx] = 0.0f;
    if (idx < 864) {
        int co = idx / 27, k = idx % 27;
        w1t[k * 32 + co] = conv1_w[idx];
    }
    if (idx < 18432) {
        int ci = idx & 31, tc = idx >> 5;
        int tap = tc >> 6, co = tc & 63;
        wpack[idx] = to_bf(conv2_w[co * 288 + ci * 9 + tap]);
    }
    if (idx < 32768) {
        int l = idx >> 12, pc = idx & 4095;
        int chunk = pc >> 4, within = pc & 15;
        int srccol = (chunk >> 1) * 16 + within;
        bias12[idx] = (chunk & 1) ? b2[l * 2048 + srccol] : b1[l * 2048 + srccol];
    }
    if (idx < 16384) {
        int b = idx >> 9, d = idx & 511;
        xa[(size_t)(b * 257) * 512 + d] = cls[d];
    }
}

// patch_w [512][64][8][8] -> bf16 [cout][tap*64+ci]
__global__ void k_pperm(const float* __restrict__ w, u16* __restrict__ wp) {
    int idx = blockIdx.x * 256 + threadIdx.x;
    int cout = idx >> 12, rem = idx & 4095;
    int tap = rem >> 6, ci = rem & 63;
    wp[idx] = to_bf(w[cout * 4096 + ci * 64 + tap]);
}

// fp32 [K][N] -> bf16 [N][K] transpose-convert (z = layer)
__global__ __launch_bounds__(256) void k_wcvtT(const float* __restrict__ src,
                                               u16* __restrict__ dst, int K, int N) {
    __shared__ float s[32][33];
    int z = blockIdx.z;
    src += (size_t)z * K * N;
    dst += (size_t)z * K * N;
    int k0 = blockIdx.y * 32, n0 = blockIdx.x * 32;
    int t = threadIdx.x, r = t >> 3, c4 = (t & 7) * 4;
    float4 v = *(const float4*)&src[(size_t)(k0 + r) * N + n0 + c4];
    s[r][c4 + 0] = v.x; s[r][c4 + 1] = v.y; s[r][c4 + 2] = v.z; s[r][c4 + 3] = v.w;
    __syncthreads();
    ushort4 o;
    o.x = to_bf(s[c4 + 0][r]); o.y = to_bf(s[c4 + 1][r]);
    o.z = to_bf(s[c4 + 2][r]); o.w = to_bf(s[c4 + 3][r]);
    *(ushort4*)&dst[(size_t)(n0 + r) * K + k0 + c4] = o;
}

// all-layer w1/w2 transpose-convert with 16-col interleaved packing
__global__ __launch_bounds__(256) void k_wcvtT12L(const float* __restrict__ w1,
                                                  const float* __restrict__ w2,
                                                  u16* __restrict__ w12All) {
    __shared__ float s[32][33];
    int z = blockIdx.z;
    int layer = z >> 1, sel = z & 1;
    const float* src = (sel ? w2 : w1) + (size_t)layer * 1048576;
    u16* dst = w12All + (size_t)layer * 2097152;
    int k0 = blockIdx.y * 32, n0 = blockIdx.x * 32;
    int t = threadIdx.x, r = t >> 3, c4 = (t & 7) * 4;
    float4 v = *(const float4*)&src[(size_t)(k0 + r) * 2048 + n0 + c4];
    s[r][c4 + 0] = v.x; s[r][c4 + 1] = v.y; s[r][c4 + 2] = v.z; s[r][c4 + 3] = v.w;
    __syncthreads();
    ushort4 o;
    o.x = to_bf(s[c4 + 0][r]); o.y = to_bf(s[c4 + 1][r]);
    o.z = to_bf(s[c4 + 2][r]); o.w = to_bf(s[c4 + 3][r]);
    int nsrc = n0 + r;
    int p = ((nsrc >> 4) << 5) + (sel << 4) + (nsrc & 15);
    *(ushort4*)&dst[(size_t)p * 512 + k0 + c4] = o;
}

// ---------------- conv1: fp32 direct, bf16 NHWC out + GN partial sums ----------------
__global__ __launch_bounds__(256) void k_conv1(const float* __restrict__ in,
                                               const float* __restrict__ wt,   // [27][32]
                                               const float* __restrict__ bias,
                                               u16* __restrict__ f1n,
                                               float* __restrict__ sacc) {
    __shared__ float s_in[3][18][18];
    __shared__ float rs[4][4], rq[4][4];
    int b = blockIdx.y;
    int tile = blockIdx.x;
    int y0 = (tile >> 3) << 4;
    int x0 = (tile & 7) << 4;
    int tid = threadIdx.x;
    for (int idx = tid; idx < 972; idx += 256) {
        int ci = idx / 324, r = idx % 324;
        int ly = r / 18, lx = r % 18;
        int gy = y0 + ly - 1, gx = x0 + lx - 1;
        float v = 0.0f;
        if (gy >= 0 && gy < 128 && gx >= 0 && gx < 128)
            v = in[((size_t)(b * 3 + ci) * 128 + gy) * 128 + gx];
        s_in[ci][ly][lx] = v;
    }
    __syncthreads();
    int py = tid >> 4, px = tid & 15;
    float acc[32];
#pragma unroll
    for (int co = 0; co < 32; co++) acc[co] = bias[co];
#pragma unroll
    for (int ci = 0; ci < 3; ci++)
#pragma unroll
        for (int dy = 0; dy < 3; dy++)
#pragma unroll
            for (int dx = 0; dx < 3; dx++) {
                float v = s_in[ci][py + dy][px + dx];
                const float* wr = &wt[(ci * 9 + dy * 3 + dx) * 32];
#pragma unroll
                for (int co = 0; co < 32; co++)
                    acc[co] = fmaf(wr[co], v, acc[co]);
            }
    float s[4] = {0.f, 0.f, 0.f, 0.f}, q[4] = {0.f, 0.f, 0.f, 0.f};
    u16 ob[32];
#pragma unroll
    for (int co = 0; co < 32; co++) {
        u16 hv = to_bf(acc[co]);
        ob[co] = hv;
        float v = to_f(hv);
        s[co >> 3] += v;
        q[co >> 3] += v * v;
    }
    int oy = y0 + py, ox = x0 + px;
    u16* dst = f1n + ((size_t)(b * 16384 + oy * 128 + ox) << 5);
#pragma unroll
    for (int i = 0; i < 8; i++)
        *(ushort4*)(dst + i * 4) = make_ushort4(ob[i * 4], ob[i * 4 + 1], ob[i * 4 + 2], ob[i * 4 + 3]);
#pragma unroll
    for (int g = 0; g < 4; g++) {
#pragma unroll
        for (int off = 1; off < 64; off <<= 1) {
            s[g] += __shfl_xor(s[g], off);
            q[g] += __shfl_xor(q[g], off);
        }
    }
    int w = tid >> 6, lane = tid & 63;
    if (lane == 0)
#pragma unroll
        for (int g = 0; g < 4; g++) { rs[g][w] = s[g]; rq[g][w] = q[g]; }
    __syncthreads();
    if (tid < 4) {
        int g = tid;
        float S = rs[g][0] + rs[g][1] + rs[g][2] + rs[g][3];
        float Q = rq[g][0] + rq[g][1] + rq[g][2] + rq[g][3];
        atomicAdd(&sacc[(b * 4 + g) * 2], S);
        atomicAdd(&sacc[(b * 4 + g) * 2 + 1], Q);
    }
}

// GN apply + GELU, bf16 NHWC in-place; stats finalized inline from sacc
__global__ void k_gnap(u16* __restrict__ xio, const float* __restrict__ sacc,
                       const float* __restrict__ gg, const float* __restrict__ bb,
                       int cm, int sh, int gmul) {
    int idx = blockIdx.x * 256 + threadIdx.x;
    long e = (long)idx * 4;
    int c0 = (int)(e & cm);
    int b = (int)(e >> sh);
    int sid = b * gmul + (c0 >> 3);
    float m = sacc[2 * sid] * (1.0f / 131072.0f);
    float var = sacc[2 * sid + 1] * (1.0f / 131072.0f) - m * m;
    float r = rsqrtf(var + 1e-5f);
    ushort4 a = *(ushort4*)&xio[e];
    ushort4 o;
    o.x = to_bf(gelu_exact((to_f(a.x) - m) * r * gg[c0 + 0] + bb[c0 + 0]));
    o.y = to_bf(gelu_exact((to_f(a.y) - m) * r * gg[c0 + 1] + bb[c0 + 1]));
    o.z = to_bf(gelu_exact((to_f(a.z) - m) * r * gg[c0 + 2] + bb[c0 + 2]));
    o.w = to_bf(gelu_exact((to_f(a.w) - m) * r * gg[c0 + 3] + bb[c0 + 3]));
    *(ushort4*)&xio[e] = o;
}

// ---------------- conv2 MFMA implicit GEMM, zero-LDS input, LDS-transposed coalesced epilogue ----------------
__global__ __launch_bounds__(256) void k_conv2m(const u16* __restrict__ f1b,
                                                const u16* __restrict__ wp,   // [9][64][32]
                                                const float* __restrict__ bias,
                                                u16* __restrict__ f2n,
                                                float* __restrict__ sacc) {
    __shared__ u16 st[256][72];
    __shared__ float rs[8][4], rq[8][4];
    int b = blockIdx.y;
    int tile = blockIdx.x;
    int y0 = (tile >> 3) << 4;
    int x0 = (tile & 7) << 4;
    int tid = threadIdx.x;
    int w = tid >> 6, lane = tid & 63;
    int l15 = lane & 15, l16 = lane >> 4;

    const u16* base = f1b + ((size_t)b << 19);

    f32x4 acc[4][4];
    f32x4 zf = {0.f, 0.f, 0.f, 0.f};
#pragma unroll
    for (int m = 0; m < 4; m++)
#pragma unroll
        for (int n = 0; n < 4; n++) acc[m][n] = zf;
    bf16x8 zb = {0, 0, 0, 0, 0, 0, 0, 0};

#pragma unroll
    for (int tap = 0; tap < 9; tap++) {
        int dy = tap / 3, dx = tap % 3;
        int gx = x0 + l15 + dx - 1;
        bf16x8 af[4], bk[4];
#pragma unroll
        for (int m = 0; m < 4; m++) {
            int gy = y0 + w * 4 + m + dy - 1;
            bool ok = (gy >= 0) && (gy < 128) && (gx >= 0) && (gx < 128);
            int pix = ok ? (gy * 128 + gx) : 0;
            bf16x8 v = *(const bf16x8*)(base + ((size_t)pix << 5) + l16 * 8);
            af[m] = ok ? v : zb;
        }
#pragma unroll
        for (int n = 0; n < 4; n++)
            bk[n] = *(const bf16x8*)&wp[(tap * 64 + n * 16 + l15) * 32 + l16 * 8];
#pragma unroll
        for (int m = 0; m < 4; m++)
#pragma unroll
            for (int n = 0; n < 4; n++)
                acc[m][n] = __builtin_amdgcn_mfma_f32_16x16x32_bf16(af[m], bk[n], acc[m][n], 0, 0, 0);
    }

#pragma unroll
    for (int n = 0; n < 4; n++) {
        int ch = n * 16 + l15;
        float bv = bias[ch];
#pragma unroll
        for (int m = 0; m < 4; m++) {
#pragma unroll
            for (int r = 0; r < 4; r++) {
                int lpix = (w * 4 + m) * 16 + l16 * 4 + r;
                st[lpix][ch] = to_bf(acc[m][n][r] + bv);
            }
        }
    }
    __syncthreads();

    int py = tid >> 4, pxx = tid & 15;
    u16* dstp = f2n + ((size_t)(b * 16384 + (y0 + py) * 128 + x0 + pxx) << 6);
    float gs[8], gq[8];
#pragma unroll
    for (int g = 0; g < 8; g++) { gs[g] = 0.0f; gq[g] = 0.0f; }
#pragma unroll
    for (int c0 = 0; c0 < 8; c0++) {
        u16x8 v = *(const u16x8*)&st[tid][c0 * 8];
        *(u16x8*)(dstp + c0 * 8) = v;
#pragma unroll
        for (int i = 0; i < 8; i++) {
            float f = to_f((u16)v[i]);
            gs[c0] += f;
            gq[c0] += f * f;
        }
    }
#pragma unroll
    for (int g = 0; g < 8; g++) {
#pragma unroll
        for (int off = 1; off < 64; off <<= 1) {
            gs[g] += __shfl_xor(gs[g], off);
            gq[g] += __shfl_xor(gq[g], off);
        }
    }
    if (lane == 0)
#pragma unroll
        for (int g = 0; g < 8; g++) { rs[g][w] = gs[g]; rq[g][w] = gq[g]; }
    __syncthreads();
    if (tid < 8) {
        int g = tid;
        float S = rs[g][0] + rs[g][1] + rs[g][2] + rs[g][3];
        float Q = rq[g][0] + rq[g][1] + rq[g][2] + rq[g][3];
        atomicAdd(&sacc[(b * 8 + g) * 2], S);
        atomicAdd(&sacc[(b * 8 + g) * 2 + 1], Q);
    }
}

// ---------------- bf16 MFMA GEMM (128x128) ----------------
// MODE 0: A [M,K]. MODE 1: implicit im2col of f2n NHWC.
// EPI 1: fp32 C = acc+bias. EPI 2: fp32 C += acc+bias. EPI 3: patch scatter + postab.
// EPI 6: interleaved w12 -> bf16 hb = silu(h1)*h2, out stride N/2.
// EPI 7: bf16 C = rope(acc+bias) for cols<1024, else acc+bias.
template <int MODE, int EPI>
__global__ __launch_bounds__(256) void k_bgemm(const u16* __restrict__ A,
                                               const u16* __restrict__ Bt,
                                               const float* __restrict__ bias,
                                               void* __restrict__ Cp,
                                               const float* __restrict__ aux,
                                               int M, int N, int K) {
    __shared__ u16 ldsA[8192];   // [kg 8][row 128][8]
    __shared__ u16 ldsB[8192];   // [col 128][kg^swz 8][8]
    int tid = threadIdx.x;
    int w = tid >> 6, lane = tid & 63;
    int bm = blockIdx.y * 128, bn = blockIdx.x * 128;
    int wr = w >> 1, wc = w & 1;
    int l15 = lane & 15, l16 = lane >> 4;

    f32x4 acc[4][4];
    f32x4 zf = {0.f, 0.f, 0.f, 0.f};
#pragma unroll
    for (int m = 0; m < 4; m++)
#pragma unroll
        for (int n = 0; n < 4; n++) acc[m][n] = zf;

    for (int k0 = 0; k0 < K; k0 += 64) {
#pragma unroll
        for (int i = 0; i < 4; i++) {
            int chunk = (w * 4 + i) * 64 + lane;
            int kg = chunk >> 7, row = chunk & 127;
            const u16* src;
            if (MODE == 0) {
                int grow = bm + row;
                if (grow > M - 1) grow = M - 1;
                src = A + (size_t)grow * K + k0 + kg * 8;
            } else {
                int grow = bm + row;
                int bimg = grow >> 8, p = grow & 255;
                int kga = (k0 >> 3) + kg;
                int tap = kga >> 3, cq = kga & 7;
                int ky = tap >> 3, kx = tap & 7;
                int gy = ((p >> 4) << 3) + ky, gx = ((p & 15) << 3) + kx;
                src = A + (((size_t)(bimg * 16384 + gy * 128 + gx)) << 6) + cq * 8;
            }
            gload_lds16(src, &ldsA[(w * 4 + i) * 512]);
        }
#pragma unroll
        for (int i = 0; i < 4; i++) {
            int chunk = (w * 4 + i) * 64 + lane;
            int col = chunk >> 3, kgs = chunk & 7;
            int kg_src = kgs ^ (col & 7);
            const u16* src = Bt + (size_t)(bn + col) * K + k0 + kg_src * 8;
            gload_lds16(src, &ldsB[(w * 4 + i) * 512]);
        }
        __syncthreads();

        bf16x8 af[4][2], bfr[4][2];
#pragma unroll
        for (int kk = 0; kk < 2; kk++) {
            int kga = kk * 4 + l16;
#pragma unroll
            for (int m = 0; m < 4; m++) {
                int row_l = wr * 64 + m * 16 + l15;
                af[m][kk] = *(const bf16x8*)&ldsA[(kga * 128 + row_l) * 8];
            }
#pragma unroll
            for (int n = 0; n < 4; n++) {
                int col_l = wc * 64 + n * 16 + l15;
                bfr[n][kk] = *(const bf16x8*)&ldsB[(col_l * 8 + (kga ^ (col_l & 7))) * 8];
            }
        }
#pragma unroll
        for (int m = 0; m < 4; m++)
#pragma unroll
            for (int n = 0; n < 4; n++) {
                acc[m][n] = __builtin_amdgcn_mfma_f32_16x16x32_bf16(af[m][0], bfr[n][0], acc[m][n], 0, 0, 0);
                acc[m][n] = __builtin_amdgcn_mfma_f32_16x16x32_bf16(af[m][1], bfr[n][1], acc[m][n], 0, 0, 0);
            }
        __syncthreads();
    }

    if (EPI == 6) {
#pragma unroll
        for (int np = 0; np < 2; np++) {
            int n_a = np * 2, n_b = np * 2 + 1;
            float bva = bias[bn + wc * 64 + n_a * 16 + l15];
            float bvb = bias[bn + wc * 64 + n_b * 16 + l15];
            int ocol = (bn >> 1) + wc * 32 + np * 16 + l15;
#pragma unroll
            for (int m = 0; m < 4; m++) {
#pragma unroll
                for (int r = 0; r < 4; r++) {
                    int grow = bm + wr * 64 + m * 16 + l16 * 4 + r;
                    if (grow < M) {
                        float h1v = to_f(to_bf(acc[m][n_a][r] + bva));
                        float h2v = to_f(to_bf(acc[m][n_b][r] + bvb));
                        float sl = h1v / (1.0f + __expf(-h1v));
                        ((u16*)Cp)[(size_t)grow * (N >> 1) + ocol] = to_bf(sl * h2v);
                    }
                }
            }
        }
    } else {
#pragma unroll
        for (int n = 0; n < 4; n++) {
            int gcol = bn + wc * 64 + n * 16 + l15;
            float bv = bias[gcol];
            float rc = 0.f, rsn = 0.f, rsc = 1.f;
            bool isqk = false, odd = false;
            if (EPI == 7) {
                isqk = gcol < 1024;
                odd = (l15 & 1) != 0;
                const float* rb = &aux[(gcol & 511) * 4];
                if (isqk) {
                    rc = rb[0]; rsn = rb[1];
                    rsc = (gcol < 512) ? rb[2] : rb[3];
                }
            }
#pragma unroll
            for (int m = 0; m < 4; m++) {
#pragma unroll
                for (int r = 0; r < 4; r++) {
                    int grow = bm + wr * 64 + m * 16 + l16 * 4 + r;
                    float v = acc[m][n][r] + bv;
                    if (EPI == 7) {
                        float p = __shfl_xor(v, 1);
                        float vr = isqk ? ((odd ? (v * rc + p * rsn) : (v * rc - p * rsn)) * rsc) : v;
                        if (grow < M) ((u16*)Cp)[(size_t)grow * N + gcol] = to_bf(vr);
                    } else if (EPI == 1) {
                        if (grow < M) ((float*)Cp)[(size_t)grow * N + gcol] = v;
                    } else if (EPI == 2) {
                        if (grow < M) ((float*)Cp)[(size_t)grow * N + gcol] += v;
                    } else {
                        int bimg = grow >> 8, p2 = grow & 255;
                        v += aux[p2 * 512 + gcol];
                        ((float*)Cp)[((size_t)(bimg * 257) + 1 + p2) * 512 + gcol] = v;
                    }
                }
            }
        }
    }
}

// ---------------- bf16 MFMA GEMM, BM=64 x BN=128 (for N=512 GEMMs; EPI2: fp32 +=) ----------------
__global__ __launch_bounds__(256) void k_bgemm64(const u16* __restrict__ A,
                                                 const u16* __restrict__ Bt,
                                                 const float* __restrict__ bias,
                                                 float* __restrict__ C,
                                                 int M, int N, int K) {
    __shared__ u16 ldsA[4096];   // [kg 8][row 64][8]
    __shared__ u16 ldsB[8192];   // [col 128][kg^swz 8][8]
    int tid = threadIdx.x;
    int w = tid >> 6, lane = tid & 63;
    int bm = blockIdx.y * 64, bn = blockIdx.x * 128;
    int l15 = lane & 15, l16 = lane >> 4;

    f32x4 acc[4][2];
    f32x4 zf = {0.f, 0.f, 0.f, 0.f};
#pragma unroll
    for (int m = 0; m < 4; m++)
#pragma unroll
        for (int n = 0; n < 2; n++) acc[m][n] = zf;

    for (int k0 = 0; k0 < K; k0 += 64) {
#pragma unroll
        for (int i = 0; i < 2; i++) {
            int chunk = (w * 2 + i) * 64 + lane;     // 0..511
            int kg = chunk >> 6, row = chunk & 63;
            int grow = bm + row;
            if (grow > M - 1) grow = M - 1;
            const u16* src = A + (size_t)grow * K + k0 + kg * 8;
            gload_lds16(src, &ldsA[(w * 2 + i) * 512]);
        }
#pragma unroll
        for (int i = 0; i < 4; i++) {
            int chunk = (w * 4 + i) * 64 + lane;
            int col = chunk >> 3, kgs = chunk & 7;
            int kg_src = kgs ^ (col & 7);
            const u16* src = Bt + (size_t)(bn + col) * K + k0 + kg_src * 8;
            gload_lds16(src, &ldsB[(w * 4 + i) * 512]);
        }
        __syncthreads();

        bf16x8 af[4][2], bfr[2][2];
#pragma unroll
        for (int kk = 0; kk < 2; kk++) {
            int kga = kk * 4 + l16;
#pragma unroll
            for (int m = 0; m < 4; m++) {
                int row_l = m * 16 + l15;
                af[m][kk] = *(const bf16x8*)&ldsA[(kga * 64 + row_l) * 8];
            }
#pragma unroll
            for (int n = 0; n < 2; n++) {
                int col_l = w * 32 + n * 16 + l15;
                bfr[n][kk] = *(const bf16x8*)&ldsB[(col_l * 8 + (kga ^ (col_l & 7))) * 8];
            }
        }
#pragma unroll
        for (int m = 0; m < 4; m++)
#pragma unroll
            for (int n = 0; n < 2; n++) {
                acc[m][n] = __builtin_amdgcn_mfma_f32_16x16x32_bf16(af[m][0], bfr[n][0], acc[m][n], 0, 0, 0);
                acc[m][n] = __builtin_amdgcn_mfma_f32_16x16x32_bf16(af[m][1], bfr[n][1], acc[m][n], 0, 0, 0);
            }
        __syncthreads();
    }

#pragma unroll
    for (int n = 0; n < 2; n++) {
        int gcol = bn + w * 32 + n * 16 + l15;
        float bv = bias[gcol];
#pragma unroll
        for (int m = 0; m < 4; m++) {
#pragma unroll
            for (int r = 0; r < 4; r++) {
                int grow = bm + m * 16 + l16 * 4 + r;
                if (grow < M) C[(size_t)grow * N + gcol] += acc[m][n][r] + bv;
            }
        }
    }
}

// ---------------- LayerNorm, wave-per-row, bf16 out ----------------
__global__ __launch_bounds__(256) void k_lnb(const float* __restrict__ x,
                                             const float* __restrict__ g,
                                             const float* __restrict__ bta,
                                             u16* __restrict__ o) {
    int row = blockIdx.x * 4 + (threadIdx.x >> 6);
    int lane = threadIdx.x & 63;
    const float4* xr = (const float4*)(x + (size_t)row * 512);
    float4 a = xr[lane * 2], b = xr[lane * 2 + 1];
    float s = a.x + a.y + a.z + a.w + b.x + b.y + b.z + b.w;
#pragma unroll
    for (int off = 1; off < 64; off <<= 1) s += __shfl_xor(s, off);
    float mean = s * (1.0f / 512.0f);
    float d[8] = {a.x - mean, a.y - mean, a.z - mean, a.w - mean,
                  b.x - mean, b.y - mean, b.z - mean, b.w - mean};
    float q = 0.0f;
#pragma unroll
    for (int i = 0; i < 8; i++) q += d[i] * d[i];
#pragma unroll
    for (int off = 1; off < 64; off <<= 1) q += __shfl_xor(q, off);
    float rstd = rsqrtf(q * (1.0f / 512.0f) + EPSV);
    int c0 = lane * 8;
    float4 g0 = *(const float4*)&g[c0], g1 = *(const float4*)&g[c0 + 4];
    float4 b0 = *(const float4*)&bta[c0], b1 = *(const float4*)&bta[c0 + 4];
    u16* orow = o + (size_t)row * 512 + c0;
    *(ushort4*)orow = make_ushort4(to_bf(d[0] * rstd * g0.x + b0.x), to_bf(d[1] * rstd * g0.y + b0.y),
                                   to_bf(d[2] * rstd * g0.z + b0.z), to_bf(d[3] * rstd * g0.w + b0.w));
    *(ushort4*)(orow + 4) = make_ushort4(to_bf(d[4] * rstd * g1.x + b1.x), to_bf(d[5] * rstd * g1.y + b1.y),
                                         to_bf(d[6] * rstd * g1.z + b1.z), to_bf(d[7] * rstd * g1.w + b1.w));
}

// final LN, wave-per-row, output remap (fp32 out)
__global__ __launch_bounds__(256) void k_ln_out(const float* __restrict__ x,
                                                const float* __restrict__ g,
                                                const float* __restrict__ bta,
                                                float* __restrict__ out) {
    int row = blockIdx.x * 4 + (threadIdx.x >> 6);
    int lane = threadIdx.x & 63;
    const float4* xr = (const float4*)(x + (size_t)row * 512);
    float4 a = xr[lane * 2], b = xr[lane * 2 + 1];
    float s = a.x + a.y + a.z + a.w + b.x + b.y + b.z + b.w;
#pragma unroll
    for (int off = 1; off < 64; off <<= 1) s += __shfl_xor(s, off);
    float mean = s * (1.0f / 512.0f);
    float d[8] = {a.x - mean, a.y - mean, a.z - mean, a.w - mean,
                  b.x - mean, b.y - mean, b.z - mean, b.w - mean};
    float q = 0.0f;
#pragma unroll
    for (int i = 0; i < 8; i++) q += d[i] * d[i];
#pragma unroll
    for (int off = 1; off < 64; off <<= 1) q += __shfl_xor(q, off);
    float rstd = rsqrtf(q * (1.0f / 512.0f) + EPSV);
    int bb = row / 257, t = row % 257;
    float* dst = (t == 0) ? out + (size_t)bb * 512
                          : out + 16384 + (size_t)(bb * 256 + (t - 1)) * 512;
    int c0 = lane * 8;
    float4 g0 = *(const float4*)&g[c0], g1 = *(const float4*)&g[c0 + 4];
    float4 b0 = *(const float4*)&bta[c0], b1 = *(const float4*)&bta[c0 + 4];
    *(float4*)(dst + c0) = make_float4(d[0] * rstd * g0.x + b0.x, d[1] * rstd * g0.y + b0.y,
                                       d[2] * rstd * g0.z + b0.z, d[3] * rstd * g0.w + b0.w);
    *(float4*)(dst + c0 + 4) = make_float4(d[4] * rstd * g1.x + b1.x, d[5] * rstd * g1.y + b1.y,
                                           d[6] * rstd * g1.z + b1.z, d[7] * rstd * g1.w + b1.w);
}

// ---------------- MFMA attention: pre-roped qkv, direct-global Q/K, dbuf PV, setprio ----------------
__global__ __launch_bounds__(256) void k_attn_mfma(const u16* __restrict__ qkv,
                                                   u16* __restrict__ y) {
    __shared__ u16 KV[2][64][72];
    __shared__ float sc[32][260];
    __shared__ u16 Pb[32][328];
    __shared__ float red1[32][8];
    __shared__ float red2[32][8];
    __shared__ float invr[32];

    int bid = blockIdx.x;                 // ((b*8+h)*9 + qt)
    int qt = bid % 9, bh = bid / 9;
    int h = bh & 7, b = bh >> 3;
    int q0 = qt * 32;
    int tid = threadIdx.x;
    int w = tid >> 6, lane = tid & 63;
    int l15 = lane & 15, l16 = lane >> 4;

    bf16x8 aq[2][2];
#pragma unroll
    for (int m = 0; m < 2; m++) {
        int grow = q0 + m * 16 + l15; if (grow > 256) grow = 256;
        const u16* qp = qkv + (size_t)(b * 257 + grow) * 1536 + h * 64 + l16 * 8;
        aq[m][0] = *(const bf16x8*)qp;
        aq[m][1] = *(const bf16x8*)(qp + 32);
    }

    for (int t = 0; t < 5; t++) {
        int j0 = t * 64;
        int gk = j0 + w * 16 + l15; if (gk > 256) gk = 256;
        const u16* kp = qkv + (size_t)(b * 257 + gk) * 1536 + 512 + h * 64 + l16 * 8;
        bf16x8 bk0 = *(const bf16x8*)kp;
        bf16x8 bk1 = *(const bf16x8*)(kp + 32);
        f32x4 a2[2];
        f32x4 zf = {0.f, 0.f, 0.f, 0.f};
        __builtin_amdgcn_s_setprio(1);
#pragma unroll
        for (int m = 0; m < 2; m++) {
            a2[m] = zf;
            a2[m] = __builtin_amdgcn_mfma_f32_16x16x32_bf16(aq[m][0], bk0, a2[m], 0, 0, 0);
            a2[m] = __builtin_amdgcn_mfma_f32_16x16x32_bf16(aq[m][1], bk1, a2[m], 0, 0, 0);
        }
        __builtin_amdgcn_s_setprio(0);
        int col = j0 + w * 16 + l15;
        if (col < 257) {
#pragma unroll
            for (int m = 0; m < 2; m++)
#pragma unroll
                for (int r = 0; r < 4; r++)
                    sc[m * 16 + l16 * 4 + r][col] = a2[m][r];
        }
    }
    __syncthreads();

    {
        int r = tid >> 3, sub = tid & 7;
        float mx = -1e30f;
        for (int j = sub; j < 257; j += 8) mx = fmaxf(mx, sc[r][j]);
        red1[r][sub] = mx;
        __syncthreads();
        mx = red1[r][0];
#pragma unroll
        for (int i = 1; i < 8; i++) mx = fmaxf(mx, red1[r][i]);
        float sm = 0.0f;
        for (int j = sub; j < 257; j += 8) {
            float e = __expf(sc[r][j] - mx);
            Pb[r][j] = to_bf(e);
            sm += e;
        }
        for (int j = 257 + sub; j < 320; j += 8) Pb[r][j] = 0;
        red2[r][sub] = sm;
        __syncthreads();
        if (sub == 0) {
            float t = red2[r][0];
#pragma unroll
            for (int i = 1; i < 8; i++) t += red2[r][i];
            invr[r] = 1.0f / t;
        }
        __syncthreads();
    }

    f32x4 oacc[2];
    {
        f32x4 zf = {0.f, 0.f, 0.f, 0.f};
        oacc[0] = zf; oacc[1] = zf;
    }
    for (int t = 0; t < 5; t++) {
        int j0 = t * 64;
        int buf = t & 1;
        {
            int vk = tid & 63, vd0 = (tid >> 6) * 16;
            int gk = j0 + vk;
            u16 o[16];
            if (gk <= 256) {
                const u16* vp = qkv + (size_t)(b * 257 + gk) * 1536 + 1024 + h * 64 + vd0;
                ushort4 a0 = *(const ushort4*)vp, a1 = *(const ushort4*)(vp + 4);
                ushort4 a2v = *(const ushort4*)(vp + 8), a3 = *(const ushort4*)(vp + 12);
                o[0] = a0.x; o[1] = a0.y; o[2] = a0.z; o[3] = a0.w;
                o[4] = a1.x; o[5] = a1.y; o[6] = a1.z; o[7] = a1.w;
                o[8] = a2v.x; o[9] = a2v.y; o[10] = a2v.z; o[11] = a2v.w;
                o[12] = a3.x; o[13] = a3.y; o[14] = a3.z; o[15] = a3.w;
            } else {
#pragma unroll
                for (int i = 0; i < 16; i++) o[i] = 0;
            }
#pragma unroll
            for (int i = 0; i < 16; i++) KV[buf][vd0 + i][vk] = o[i];
        }
        __syncthreads();

        bf16x8 ap[2][2], bv[2];
#pragma unroll
        for (int m = 0; m < 2; m++)
#pragma unroll
            for (int kk = 0; kk < 2; kk++)
                ap[m][kk] = *(const bf16x8*)&Pb[m * 16 + l15][j0 + kk * 32 + l16 * 8];
#pragma unroll
        for (int kk = 0; kk < 2; kk++)
            bv[kk] = *(const bf16x8*)&KV[buf][w * 16 + l15][kk * 32 + l16 * 8];
        __builtin_amdgcn_s_setprio(1);
#pragma unroll
        for (int m = 0; m < 2; m++) {
            oacc[m] = __builtin_amdgcn_mfma_f32_16x16x32_bf16(ap[m][0], bv[0], oacc[m], 0, 0, 0);
            oacc[m] = __builtin_amdgcn_mfma_f32_16x16x32_bf16(ap[m][1], bv[1], oacc[m], 0, 0, 0);
        }
        __builtin_amdgcn_s_setprio(0);
    }

#pragma unroll
    for (int m = 0; m < 2; m++)
#pragma unroll
        for (int r = 0; r < 4; r++) {
            int lr = m * 16 + l16 * 4 + r;
            int grow = q0 + lr;
            if (grow < 257)
                y[(size_t)(b * 257 + grow) * 512 + h * 64 + w * 16 + l15] =
                    to_bf(oacc[m][r] * invr[lr]);
        }
}

// ---------------- host launch ----------------
extern "C" void kernel_launch(void* const* d_in, const int* in_sizes, int n_in,
                              void* d_out, int out_size, void* d_ws, size_t ws_size,
                              hipStream_t stream) {
    const float* x       = (const float*)d_in[0];
    const float* conv1_w = (const float*)d_in[1];
    const float* conv1_b = (const float*)d_in[2];
    const float* gn1_g   = (const float*)d_in[3];
    const float* gn1_b   = (const float*)d_in[4];
    const float* conv2_w = (const float*)d_in[5];
    const float* conv2_b = (const float*)d_in[6];
    const float* gn2_g   = (const float*)d_in[7];
    const float* gn2_b   = (const float*)d_in[8];
    const float* patch_w = (const float*)d_in[9];
    const float* patch_b = (const float*)d_in[10];
    const float* cls_tok = (const float*)d_in[11];
    const float* ln1_g   = (const float*)d_in[12];
    const float* ln1_b   = (const float*)d_in[13];
    const float* qkv_w   = (const float*)d_in[14];
    const float* qkv_b   = (const float*)d_in[15];
    const float* out_w   = (const float*)d_in[16];
    const float* out_b   = (const float*)d_in[17];
    const float* ln2_g   = (const float*)d_in[18];
    const float* ln2_b   = (const float*)d_in[19];
    const float* w1_w    = (const float*)d_in[20];
    const float* w1_b    = (const float*)d_in[21];
    const float* w2_w    = (const float*)d_in[22];
    const float* w2_b    = (const float*)d_in[23];
    const float* w3_w    = (const float*)d_in[24];
    const float* w3_b    = (const float*)d_in[25];
    const float* fn_g    = (const float*)d_in[26];
    const float* fn_b    = (const float*)d_in[27];
    float* out = (float*)d_out;
    char* wsb  = (char*)d_ws;

    const size_t O_R1    = 0;
    const size_t O_W12A  = 0;
    const size_t O_W3A   = 33554432;
    const size_t O_HB    = O_R1 + 67371008;
    const size_t O_NB    = O_R1 + 101056512;
    const size_t O_Y     = O_R1 + 109477888;
    const size_t O_R2    = 134217728;
    const size_t O_XA    = 201326592;
    const size_t O_PWT   = 218169344;
    const size_t O_QKVT  = 222363648;
    const size_t O_OUTT  = 234946560;
    const size_t O_PT    = 245432320;
    const size_t O_RT    = 245956608;
    const size_t O_CW1   = 245964800;
    const size_t O_CW2   = 245968896;
    const size_t O_SA    = 246046720;
    const size_t O_B12   = 246050816;
    const size_t NEED    = 246181888;
    if (ws_size < NEED) {
        k_wsfail<<<1, 1, 0, stream>>>(out);
        return;
    }
    u16*   f2n    = (u16*)(wsb + O_R1);
    u16*   w12All = (u16*)(wsb + O_W12A);
    u16*   w3All  = (u16*)(wsb + O_W3A);
    u16*   hb     = (u16*)(wsb + O_HB);
    u16*   nb     = (u16*)(wsb + O_NB);
    u16*   yb     = (u16*)(wsb + O_Y);
    u16*   f1n    = (u16*)(wsb + O_R2);
    u16*   qkvb   = (u16*)(wsb + O_R2);
    float* xa     = (float*)(wsb + O_XA);
    u16*   patchT = (u16*)(wsb + O_PWT);
    u16*   qkvT   = (u16*)(wsb + O_QKVT);
    u16*   outT   = (u16*)(wsb + O_OUTT);
    float* postab = (float*)(wsb + O_PT);
    float* ropet  = (float*)(wsb + O_RT);
    float* w1t    = (float*)(wsb + O_CW1);
    u16*   wpack  = (u16*)(wsb + O_CW2);
    float* sacc   = (float*)(wsb + O_SA);
    float* bias12 = (float*)(wsb + O_B12);

    // setup + persistent weight conversions
    k_setup<<<512, 256, 0, stream>>>(sacc, conv1_w, w1t, conv2_w, wpack,
                                     w1_b, w2_b, bias12, postab, ropet, cls_tok, xa);
    k_pperm<<<8192, 256, 0, stream>>>(patch_w, patchT);
    k_wcvtT<<<dim3(48, 16, 8), 256, 0, stream>>>(qkv_w, qkvT, 512, 1536);
    k_wcvtT<<<dim3(16, 16, 8), 256, 0, stream>>>(out_w, outT, 512, 512);

    // conv stem (NHWC bf16, fused GN stats)
    k_conv1<<<dim3(64, 32), 256, 0, stream>>>(x, w1t, conv1_b, f1n, sacc);
    k_gnap<<<16384, 256, 0, stream>>>(f1n, sacc, gn1_g, gn1_b, 31, 19, 4);
    k_conv2m<<<dim3(64, 32), 256, 0, stream>>>(f1n, wpack, conv2_b, f2n, sacc + 256);
    k_gnap<<<32768, 256, 0, stream>>>(f2n, sacc + 256, gn2_g, gn2_b, 63, 20, 8);

    // patch embed (frees region 0 afterwards)
    k_bgemm<1, 3><<<dim3(4, 64), 256, 0, stream>>>(f2n, patchT, patch_b, xa, postab, 8192, 512, 4096);

    // one-time all-layer MLP weight conversion into freed region
    k_wcvtT12L<<<dim3(64, 16, 16), 256, 0, stream>>>(w1_w, w2_w, w12All);
    k_wcvtT<<<dim3(16, 64, 8), 256, 0, stream>>>(w3_w, w3All, 2048, 512);

    // transformer
    for (int l = 0; l < 8; l++) {
        k_lnb<<<2056, 256, 0, stream>>>(xa, ln1_g + l * 512, ln1_b + l * 512, nb);
        k_bgemm<0, 7><<<dim3(12, 65), 256, 0, stream>>>(nb, qkvT + (size_t)l * 786432,
                                                        qkv_b + l * 1536, qkvb, ropet, 8224, 1536, 512);
        k_attn_mfma<<<2304, 256, 0, stream>>>(qkvb, yb);
        k_bgemm64<<<dim3(4, 129), 256, 0, stream>>>(yb, outT + (size_t)l * 262144,
                                                    out_b + l * 512, xa, 8224, 512, 512);
        k_lnb<<<2056, 256, 0, stream>>>(xa, ln2_g + l * 512, ln2_b + l * 512, nb);
        k_bgemm<0, 6><<<dim3(32, 65), 256, 0, stream>>>(nb, w12All + (size_t)l * 2097152,
                                                        bias12 + l * 4096, hb, nullptr, 8224, 4096, 512);
        k_bgemm64<<<dim3(4, 129), 256, 0, stream>>>(hb, w3All + (size_t)l * 1048576,
                                                    w3_b + l * 512, xa, 8224, 512, 2048);
    }
    k_ln_out<<<2056, 256, 0, stream>>>(xa, fn_g, fn_b, out);
}